// Round 15
// baseline (921.524 us; speedup 1.0000x reference)
//
#include <hip/hip_runtime.h>

// Frequency-domain room sim, 3-kernel phase split.
//   SF = DFT(sound_field) per cell (unnormalized); per block b:
//     T = clip(res,0,1) * (SF + DFT(env_b));  mic_b = IDFT(T[mic])/1024;
//     SF = box3x3x3(T)   (pointwise per bin -> recursion independent per bin)
// P1: radix-4^5 env FFTs, 4 pts/thread, 4 cells/WG, ONE 16 KB LDS buffer.
//     Grid 2048 (8 WG/CU), 8 items/WG, XCD-contiguous item map. RAW barriers
//     (lgkmcnt-only + s_barrier) so vmcnt floats: stores + next-item noise
//     prefetch stay in flight across all FFT passes (rounds 10-14 showed the
//     pipes serialize at ~253us because __syncthreads drains vmcnt(0)).
//     SWX bank swizzle: conflict-optimal for strides {256,64,16,4,1}+linear.
// P2: 512 WGs x 1024 threads (round-14 form, verified). WG0 = bins {0,512}.
// P3: 16 inverse FFTs of the mic spectra.

#define NFFT   1024
#define NF     513
#define NKP    257
#define NCELLS 4096
#define NPAIR  2048
#define PI2    6.28318530717958647692f

// raw workgroup barrier: order LDS only; global loads/stores keep flowing
#define RBAR() do { \
    asm volatile("s_waitcnt lgkmcnt(0)" ::: "memory"); \
    __builtin_amdgcn_s_barrier(); \
    __builtin_amdgcn_sched_barrier(0); \
} while (0)

// float4-index XOR swizzle, bijective on [0,1024): per-16-lane bank spread
// is exactly 2x per bank-quad for all pass strides (hand-derived r15).
__device__ __forceinline__ int SWX(int i) {
    return i ^ ((i >> 3) & 7) ^ ((i >> 6) & 7);
}
// base-4 digit reversal of a 10-bit index (5 digits)
__device__ __forceinline__ int slotof4(int k) {
    return ((k & 3) << 8) | (((k >> 2) & 3) << 6) | (((k >> 4) & 3) << 4) |
           (((k >> 6) & 3) << 2) | ((k >> 8) & 3);
}
__device__ __forceinline__ float clip01(float v) { return fminf(fmaxf(v, 0.0f), 1.0f); }
__device__ __forceinline__ unsigned pkh2(float a, float b) {
    union { _Float16 h[2]; unsigned u; } z;
    z.h[0] = (_Float16)a; z.h[1] = (_Float16)b;
    return z.u;
}
__device__ __forceinline__ float h2lo(unsigned u) {
    union { unsigned u; _Float16 h[2]; } z; z.u = u; return (float)z.h[0];
}
__device__ __forceinline__ float h2hi(unsigned u) {
    union { unsigned u; _Float16 h[2]; } z; z.u = u; return (float)z.h[1];
}
__device__ __forceinline__ unsigned cmp4(const uint4& v, int c) {
    return c == 0 ? v.x : c == 1 ? v.y : c == 2 ? v.z : v.w;
}
__device__ __forceinline__ float4 f4add(float4 a, float4 b) {
    return make_float4(a.x + b.x, a.y + b.y, a.z + b.z, a.w + b.w);
}
__device__ __forceinline__ float4 f4sub(float4 a, float4 b) {
    return make_float4(a.x - b.x, a.y - b.y, a.z - b.z, a.w - b.w);
}
__device__ __forceinline__ float4 cmul2(float4 d, float2 w) {
    return make_float4(d.x * w.x - d.y * w.y, d.x * w.y + d.y * w.x,
                       d.z * w.x - d.w * w.y, d.z * w.y + d.w * w.x);
}
__device__ __forceinline__ float4 nI(float4 v) { return make_float4(v.y, -v.x, v.w, -v.z); }
__device__ __forceinline__ float4 pI(float4 v) { return make_float4(-v.y, v.x, -v.w, v.z); }

__device__ __forceinline__ void dft4(float4* a) {
    float4 e = f4add(a[0], a[2]), f = f4add(a[1], a[3]);
    float4 g = f4sub(a[0], a[2]), h = f4sub(a[1], a[3]);
    a[0] = f4add(e, f);
    a[2] = f4sub(e, f);
    a[1] = f4add(g, nI(h));
    a[3] = f4add(g, pI(h));
}

__device__ __forceinline__ void twiddle3(float4* a, int j, float invL) {
    float sv, cv;
    __sincosf(-PI2 * (float)j * invL, &sv, &cv);
    float2 w1 = make_float2(cv, sv), wp = w1;
    a[1] = cmul2(a[1], wp);
    wp = make_float2(wp.x * w1.x - wp.y * w1.y, wp.x * w1.y + wp.y * w1.x);
    a[2] = cmul2(a[2], wp);
    wp = make_float2(wp.x * w1.x - wp.y * w1.y, wp.x * w1.y + wp.y * w1.x);
    a[3] = cmul2(a[3], wp);
}

// ---------------- P1 ----------------
// Grid 2048 (8 WG/CU). WG handles 8 items; item = (xcd<<11) + (t<<8) + lw.
// At each t, an XCD's 256 WGs cover 256 consecutive cell-groups -> Et store
// sectors merge in that XCD's L2.
__global__ __launch_bounds__(256, 8) void k_p1(
    const float* __restrict__ tf, const float* __restrict__ imp,
    const float* __restrict__ noise, unsigned* __restrict__ Et,
    unsigned* __restrict__ TFt)
{
    __shared__ float4 FD[1024];        // exactly 16 KB

    const int tid = threadIdx.x;
    const int xcd = blockIdx.x & 7, lw = blockIdx.x >> 3;

    // preload item t=0 noise
    float nzA[16];
    {
        const int item = (xcd << 11) | lw;
        const int b = item >> 10, c0 = (item & 1023) << 2;
        const float* nz = noise + ((size_t)b * NCELLS + c0) * (size_t)NFFT + tid;
        #pragma unroll
        for (int m = 0; m < 4; ++m)
            #pragma unroll
            for (int cc = 0; cc < 4; ++cc)
                nzA[4 * m + cc] = nz[cc * NFFT + (m << 8)];
    }

    #pragma unroll 1
    for (int t = 0; t < 8; ++t) {
        const int item = (xcd << 11) + (t << 8) + lw;
        const int b = item >> 10, c0 = (item & 1023) << 2;

        RBAR();   // previous item's FD reads complete in all waves

        // ---- env + pass0 (s=256) from registers ----
        {
            const float* ipr = imp + ((size_t)b * NCELLS + c0) * 16;
            float4 a[4];
            #pragma unroll
            for (int m = 0; m < 4; ++m) {
                int n = tid + (m << 8);
                float coord = (n + 0.5f) * (16.0f / 1024.0f) - 0.5f;
                coord = fminf(fmaxf(coord, 0.0f), 15.0f);
                int lo = (int)coord;
                int hi = lo + 1 > 15 ? 15 : lo + 1;
                float wl = coord - (float)lo, wh = 1.0f - wl;
                float4 e;
                e.x = clip01(ipr[lo]      * wh + ipr[hi]      * wl) * nzA[4 * m + 0];
                e.y = clip01(ipr[16 + lo] * wh + ipr[16 + hi] * wl) * nzA[4 * m + 1];
                e.z = clip01(ipr[32 + lo] * wh + ipr[32 + hi] * wl) * nzA[4 * m + 2];
                e.w = clip01(ipr[48 + lo] * wh + ipr[48 + hi] * wl) * nzA[4 * m + 3];
                a[m] = e;
            }

            // prefetch next item's noise (consumed next iteration; the loads
            // float across all raw barriers -> hidden under this item's work)
            if (t < 7) {
                const int ni  = (xcd << 11) + ((t + 1) << 8) + lw;
                const int nb  = ni >> 10, nc0 = (ni & 1023) << 2;
                const float* nz = noise + ((size_t)nb * NCELLS + nc0) * (size_t)NFFT + tid;
                #pragma unroll
                for (int m = 0; m < 4; ++m)
                    #pragma unroll
                    for (int cc = 0; cc < 4; ++cc)
                        nzA[4 * m + cc] = nz[cc * NFFT + (m << 8)];
            }

            dft4(a);
            twiddle3(a, tid, 1.0f / 1024.0f);
            #pragma unroll
            for (int p = 0; p < 4; ++p) FD[SWX(tid + (p << 8))] = a[p];
        }
        RBAR();

        // ---- passes s = 64, 16, 4 ----
        #pragma unroll
        for (int pi = 0; pi < 3; ++pi) {
            const int lgs = 6 - 2 * pi;
            const int s   = 1 << lgs;
            const int j   = tid & (s - 1);
            const int idx0 = ((tid >> lgs) << (lgs + 2)) | j;
            float4 a[4];
            #pragma unroll
            for (int m = 0; m < 4; ++m) a[m] = FD[SWX(idx0 + (m << lgs))];
            dft4(a);
            twiddle3(a, j, 1.0f / (float)(s << 2));
            #pragma unroll
            for (int p = 0; p < 4; ++p) FD[SWX(idx0 + (p << lgs))] = a[p];
            RBAR();
        }

        // ---- pass s=1 (trivial twiddle) ----
        {
            const int idx0 = tid << 2;
            float4 a[4];
            #pragma unroll
            for (int m = 0; m < 4; ++m) a[m] = FD[SWX(idx0 + m)];
            dft4(a);
            #pragma unroll
            for (int p = 0; p < 4; ++p) FD[SWX(idx0 + p)] = a[p];
        }
        RBAR();

        // ---- extract: linear slot read -> fp16 pack -> 8B store/lane ----
        {
            unsigned* base = Et + (size_t)b * NFFT * NPAIR + (c0 >> 1);
            #pragma unroll
            for (int it = 0; it < 4; ++it) {
                int s = tid + (it << 8);
                float4 v = FD[SWX(s)];
                uint2 u = { pkh2(v.x, v.y), pkh2(v.z, v.w) };
                *(uint2*)(base + (size_t)s * NPAIR) = u;
            }
        }

        // ---- tf: clip + pack bin pairs for 4 cells ----
        {
            const float* r0 = tf + ((size_t)b * NCELLS + c0) * NF;
            const float* r1 = r0 + NF;
            const float* r2 = r1 + NF;
            const float* r3 = r2 + NF;
            for (int kp = tid; kp < NKP; kp += 256) {
                bool hv = kp < 256;
                uint4 u;
                u.x = pkh2(clip01(r0[2 * kp]), hv ? clip01(r0[2 * kp + 1]) : 0.0f);
                u.y = pkh2(clip01(r1[2 * kp]), hv ? clip01(r1[2 * kp + 1]) : 0.0f);
                u.z = pkh2(clip01(r2[2 * kp]), hv ? clip01(r2[2 * kp + 1]) : 0.0f);
                u.w = pkh2(clip01(r3[2 * kp]), hv ? clip01(r3[2 * kp + 1]) : 0.0f);
                *(uint4*)(TFt + ((size_t)b * NKP + kp) * NCELLS + c0) = u;
            }
        }
    }
}

// ---------------- P2 ----------------
// Grid 512 x 1024 threads. Thread q: x = q>>6, y = (q>>2)&15, z-slab (q&3)*4;
// pairs 2q,2q+1. z-exchange via in-wave shfl; y/x via 32KB swizzled LDS.
// WG0 = bins {0,512} (both exactly real), rows slotof4(0)=0 / slotof4(512)=2.
__global__ __launch_bounds__(1024, 8) void k_p2(
    const unsigned* __restrict__ Et, const unsigned* __restrict__ TFt,
    float2* __restrict__ ms)
{
    __shared__ float2 Sz[4096];        // 32 KB

    const int q    = threadIdx.x;
    const int lane = q & 63;
    const int k    = blockIdx.x;
    const bool dual = (k == 0);
    const int kp  = dual ? 0 : (k >> 1);
    const int sel = dual ? 0 : (k & 1);
    const int rA  = slotof4(dual ? 0 : k);
    const int rB  = slotof4(dual ? 512 : ((1024 - k) & 1023));
    const int x = q >> 6, y = (q >> 2) & 15, zs = (q & 3) << 2;

    #define AX(qq, dz) (((qq) << 2) | ((dz) ^ ((qq) & 3) ^ (((qq) >> 2) & 3)))

    float2 SF[4];
    #pragma unroll
    for (int dz = 0; dz < 4; ++dz) SF[dz] = make_float2(0.f, 0.f);

    #pragma unroll 1
    for (int b = 0; b < 16; ++b) {
        const uint2 ea = *(const uint2*)(Et + ((size_t)b * NFFT + rA) * NPAIR + 2 * q);
        const uint2 eb = *(const uint2*)(Et + ((size_t)b * NFFT + rB) * NPAIR + 2 * q);
        const uint4 tp = *(const uint4*)(TFt + ((size_t)b * NKP + kp) * NCELLS + 4 * q);
        uint4 tp2;
        if (dual) tp2 = *(const uint4*)(TFt + ((size_t)b * NKP + 256) * NCELLS + 4 * q);

        float2 T[4];
        if (!dual) {
            #pragma unroll
            for (int j = 0; j < 2; ++j) {
                unsigned fu = j ? ea.y : ea.x;
                unsigned gu = j ? eb.y : eb.x;
                float fr = h2lo(fu), fi = h2hi(fu);
                float gr = h2lo(gu), gi = h2hi(gu);
                float ear = 0.5f * (fr + gr), eai = 0.5f * (fi - gi);
                float ebr = 0.5f * (fi + gi), ebi = 0.5f * (gr - fr);
                unsigned te = cmp4(tp, 2 * j);
                unsigned to = cmp4(tp, 2 * j + 1);
                float re_ = sel ? h2hi(te) : h2lo(te);
                float ro_ = sel ? h2hi(to) : h2lo(to);
                T[2 * j]     = make_float2(re_ * (SF[2 * j].x + ear),
                                           re_ * (SF[2 * j].y + eai));
                T[2 * j + 1] = make_float2(ro_ * (SF[2 * j + 1].x + ebr),
                                           ro_ * (SF[2 * j + 1].y + ebi));
            }
        } else {
            #pragma unroll
            for (int dz = 0; dz < 4; ++dz) {
                unsigned fu = (dz >> 1) ? ea.y : ea.x;
                unsigned gu = (dz >> 1) ? eb.y : eb.x;
                float e0   = (dz & 1) ? h2hi(fu) : h2lo(fu);
                float e512 = (dz & 1) ? h2hi(gu) : h2lo(gu);
                float tA = h2lo(cmp4(tp, dz));
                float tB = h2lo(cmp4(tp2, dz));
                T[dz] = make_float2(tA * (SF[dz].x + e0),
                                    tB * (SF[dz].y + e512));
            }
        }
        if (q == 546) {                 // cell (8,8,8)
            if (dual) {
                ms[b * NF + 0]   = make_float2(T[0].x, 0.0f);
                ms[b * NF + 512] = make_float2(T[0].y, 0.0f);
            } else {
                ms[b * NF + k] = T[0];
            }
        }

        // z-sum: slab-internal + shfl partners q-1 / q+1
        float2 D, U;
        D.x = __shfl(T[3].x, lane - 1, 64); D.y = __shfl(T[3].y, lane - 1, 64);
        U.x = __shfl(T[0].x, lane + 1, 64); U.y = __shfl(T[0].y, lane + 1, 64);
        float2 Z[4];
        Z[0] = make_float2(T[0].x + T[1].x + (zs > 0 ? D.x : 0.f),
                           T[0].y + T[1].y + (zs > 0 ? D.y : 0.f));
        Z[1] = make_float2(T[0].x + T[1].x + T[2].x, T[0].y + T[1].y + T[2].y);
        Z[2] = make_float2(T[1].x + T[2].x + T[3].x, T[1].y + T[2].y + T[3].y);
        Z[3] = make_float2(T[2].x + T[3].x + (zs < 12 ? U.x : 0.f),
                           T[2].y + T[3].y + (zs < 12 ? U.y : 0.f));

        // y-sum via LDS (neighbor q +- 4)
        #pragma unroll
        for (int dz = 0; dz < 4; ++dz) Sz[AX(q, dz)] = Z[dz];
        __syncthreads();
        #pragma unroll
        for (int dz = 0; dz < 4; ++dz) {
            float2 s = Z[dz];
            if (y > 0)  { float2 u = Sz[AX(q - 4, dz)]; s.x += u.x; s.y += u.y; }
            if (y < 15) { float2 u = Sz[AX(q + 4, dz)]; s.x += u.x; s.y += u.y; }
            Z[dz] = s;
        }
        __syncthreads();
        // x-sum via LDS (neighbor q +- 64)
        #pragma unroll
        for (int dz = 0; dz < 4; ++dz) Sz[AX(q, dz)] = Z[dz];
        __syncthreads();
        #pragma unroll
        for (int dz = 0; dz < 4; ++dz) {
            float2 s = Z[dz];
            if (x > 0)  { float2 u = Sz[AX(q - 64, dz)]; s.x += u.x; s.y += u.y; }
            if (x < 15) { float2 u = Sz[AX(q + 64, dz)]; s.x += u.x; s.y += u.y; }
            SF[dz] = s;
        }
        __syncthreads();
    }
    #undef AX
}

// ---------------- P3 ----------------
__device__ __forceinline__ int pd(int i) { return i + (i >> 5); }

__global__ __launch_bounds__(256) void k_p3(
    const float2* __restrict__ ms, float* __restrict__ out)
{
    __shared__ float2 FD[1056];
    const int b = blockIdx.x, tid = threadIdx.x;

    for (int j = tid; j < NFFT; j += 256) {
        int jj = (j <= 512) ? j : 1024 - j;
        float2 v = ms[b * NF + jj];
        if (j > 512) v.y = -v.y;
        FD[pd(__brev(j) >> 22)] = v;
    }
    __syncthreads();

    for (int lg = 0; lg <= 9; ++lg) {
        const int len = 1 << lg;
        for (int pr = tid; pr < 512; pr += 256) {
            const int jj = pr & (len - 1);
            const int i0 = ((pr >> lg) << (lg + 1)) + jj;
            const int i1 = i0 + len;
            const int iw = jj << (9 - lg);
            float sn, cs;
            __sincosf(-PI2 * (1.0f / 1024.0f) * (float)iw, &sn, &cs);
            float2 a = FD[pd(i0)], bb = FD[pd(i1)];
            float tr = bb.x * cs + bb.y * sn;
            float ti = bb.y * cs - bb.x * sn;
            FD[pd(i0)] = make_float2(a.x + tr, a.y + ti);
            FD[pd(i1)] = make_float2(a.x - tr, a.y - ti);
        }
        __syncthreads();
    }
    for (int t = tid; t < NFFT; t += 256)
        out[b * NFFT + t] = FD[pd(t)].x * (1.0f / 1024.0f);
}

extern "C" void kernel_launch(void* const* d_in, const int* in_sizes, int n_in,
                              void* d_out, int out_size, void* d_ws, size_t ws_size,
                              hipStream_t stream)
{
    const float* tf    = (const float*)d_in[1];
    const float* imp   = (const float*)d_in[2];
    const float* noise = (const float*)d_in[3];
    float* out = (float*)d_out;

    unsigned* Et  = (unsigned*)d_ws;                              // 16*1024*2048 u32
    unsigned* TFt = Et + (size_t)16 * NFFT * NPAIR;               // 16*257*4096 u32
    float2*   ms  = (float2*)(TFt + (size_t)16 * NKP * NCELLS);   // 16*513 c64

    k_p1<<<2048, 256, 0, stream>>>(tf, imp, noise, Et, TFt);
    k_p2<<<512, 1024, 0, stream>>>(Et, TFt, ms);
    k_p3<<<16, 256, 0, stream>>>(ms, out);
}

// Round 16
// 235.250 us; speedup vs baseline: 3.9172x; 3.9172x over previous
//
#include <hip/hip_runtime.h>

// Frequency-domain room sim, 4-kernel phase split.
//   SF = DFT(sound_field) per cell (unnormalized); per block b:
//     T = clip(res,0,1) * (SF + DFT(env_b));  mic_b = IDFT(T[mic])/1024;
//     SF = box3x3x3(T)   (pointwise per bin -> recursion independent per bin)
// P1: radix-4^5 env FFTs, 4 pts/thread, 4 cells/WG (= group g), 16 KB LDS,
//     8 WG/CU. ALL stores group-major & fully coalesced: Et_g[b][g][slot]
//     (uint2/slot, 8KB contiguous per WG) and TFt_g[b][g][kp] (uint4/kp).
//     Rounds 10-15 isolated a ~1 sector-write/cycle/XCD wall on the old
//     8-16B scattered stores (~6M transactions ~= 253us, invariant to
//     occupancy/conflicts); this removes every sub-line store.
// T:  tile transpose (LDS, both sides full-line, input L3-hot):
//     Et_g -> Et[b][slot][pair]; TFt_g -> TFt[b][kp][cell].
// P2: 512 WGs x 1024 threads (round-14 verified form, byte-identical reads).
// P3: 16 inverse FFTs of the mic spectra.

#define NFFT   1024
#define NF     513
#define NKP    257
#define NCELLS 4096
#define NPAIR  2048
#define PI2    6.28318530717958647692f

// raw workgroup barrier: order LDS only; global loads/stores keep flowing
#define RBAR() do { \
    asm volatile("s_waitcnt lgkmcnt(0)" ::: "memory"); \
    __builtin_amdgcn_s_barrier(); \
    __builtin_amdgcn_sched_barrier(0); \
} while (0)

// float4-index XOR swizzle (round-15 verified: conflicts 14.7M -> 4.2M)
__device__ __forceinline__ int SWX(int i) {
    return i ^ ((i >> 3) & 7) ^ ((i >> 6) & 7);
}
// base-4 digit reversal of a 10-bit index (5 digits)
__device__ __forceinline__ int slotof4(int k) {
    return ((k & 3) << 8) | (((k >> 2) & 3) << 6) | (((k >> 4) & 3) << 4) |
           (((k >> 6) & 3) << 2) | ((k >> 8) & 3);
}
__device__ __forceinline__ float clip01(float v) { return fminf(fmaxf(v, 0.0f), 1.0f); }
__device__ __forceinline__ unsigned pkh2(float a, float b) {
    union { _Float16 h[2]; unsigned u; } z;
    z.h[0] = (_Float16)a; z.h[1] = (_Float16)b;
    return z.u;
}
__device__ __forceinline__ float h2lo(unsigned u) {
    union { unsigned u; _Float16 h[2]; } z; z.u = u; return (float)z.h[0];
}
__device__ __forceinline__ float h2hi(unsigned u) {
    union { unsigned u; _Float16 h[2]; } z; z.u = u; return (float)z.h[1];
}
__device__ __forceinline__ unsigned cmp4(const uint4& v, int c) {
    return c == 0 ? v.x : c == 1 ? v.y : c == 2 ? v.z : v.w;
}
__device__ __forceinline__ float4 f4add(float4 a, float4 b) {
    return make_float4(a.x + b.x, a.y + b.y, a.z + b.z, a.w + b.w);
}
__device__ __forceinline__ float4 f4sub(float4 a, float4 b) {
    return make_float4(a.x - b.x, a.y - b.y, a.z - b.z, a.w - b.w);
}
__device__ __forceinline__ float4 cmul2(float4 d, float2 w) {
    return make_float4(d.x * w.x - d.y * w.y, d.x * w.y + d.y * w.x,
                       d.z * w.x - d.w * w.y, d.z * w.y + d.w * w.x);
}
__device__ __forceinline__ float4 nI(float4 v) { return make_float4(v.y, -v.x, v.w, -v.z); }
__device__ __forceinline__ float4 pI(float4 v) { return make_float4(-v.y, v.x, -v.w, v.z); }

__device__ __forceinline__ void dft4(float4* a) {
    float4 e = f4add(a[0], a[2]), f = f4add(a[1], a[3]);
    float4 g = f4sub(a[0], a[2]), h = f4sub(a[1], a[3]);
    a[0] = f4add(e, f);
    a[2] = f4sub(e, f);
    a[1] = f4add(g, nI(h));
    a[3] = f4add(g, pI(h));
}

__device__ __forceinline__ void twiddle3(float4* a, int j, float invL) {
    float sv, cv;
    __sincosf(-PI2 * (float)j * invL, &sv, &cv);
    float2 w1 = make_float2(cv, sv), wp = w1;
    a[1] = cmul2(a[1], wp);
    wp = make_float2(wp.x * w1.x - wp.y * w1.y, wp.x * w1.y + wp.y * w1.x);
    a[2] = cmul2(a[2], wp);
    wp = make_float2(wp.x * w1.x - wp.y * w1.y, wp.x * w1.y + wp.y * w1.x);
    a[3] = cmul2(a[3], wp);
}

// ---------------- P1 ----------------
// Grid 16384 = 16 blocks x 1024 groups. WG = group g = cells 4g..4g+3.
__global__ __launch_bounds__(256, 8) void k_p1(
    const float* __restrict__ tf, const float* __restrict__ imp,
    const float* __restrict__ noise, uint2* __restrict__ Etg,
    uint4* __restrict__ TFtg)
{
    __shared__ float4 FD[1024];        // exactly 16 KB

    const int tid = threadIdx.x;
    const int bid = blockIdx.x;
    const int b   = bid >> 10;
    const int g   = bid & 1023;
    const int c0  = g << 2;

    // ---- env + pass0 (s=256) from registers ----
    {
        const float* nz = noise + ((size_t)b * NCELLS + c0) * (size_t)NFFT + tid;
        float nzv[16];
        #pragma unroll
        for (int m = 0; m < 4; ++m)
            #pragma unroll
            for (int cc = 0; cc < 4; ++cc)
                nzv[4 * m + cc] = nz[cc * NFFT + (m << 8)];

        const float* ipr = imp + ((size_t)b * NCELLS + c0) * 16;
        float4 a[4];
        #pragma unroll
        for (int m = 0; m < 4; ++m) {
            int n = tid + (m << 8);
            float coord = (n + 0.5f) * (16.0f / 1024.0f) - 0.5f;
            coord = fminf(fmaxf(coord, 0.0f), 15.0f);
            int lo = (int)coord;
            int hi = lo + 1 > 15 ? 15 : lo + 1;
            float wl = coord - (float)lo, wh = 1.0f - wl;
            float4 e;
            e.x = clip01(ipr[lo]      * wh + ipr[hi]      * wl) * nzv[4 * m + 0];
            e.y = clip01(ipr[16 + lo] * wh + ipr[16 + hi] * wl) * nzv[4 * m + 1];
            e.z = clip01(ipr[32 + lo] * wh + ipr[32 + hi] * wl) * nzv[4 * m + 2];
            e.w = clip01(ipr[48 + lo] * wh + ipr[48 + hi] * wl) * nzv[4 * m + 3];
            a[m] = e;
        }
        dft4(a);
        twiddle3(a, tid, 1.0f / 1024.0f);
        #pragma unroll
        for (int p = 0; p < 4; ++p) FD[SWX(tid + (p << 8))] = a[p];
    }
    RBAR();

    // ---- passes s = 64, 16, 4 ----
    #pragma unroll
    for (int pi = 0; pi < 3; ++pi) {
        const int lgs = 6 - 2 * pi;
        const int s   = 1 << lgs;
        const int j   = tid & (s - 1);
        const int idx0 = ((tid >> lgs) << (lgs + 2)) | j;
        float4 a[4];
        #pragma unroll
        for (int m = 0; m < 4; ++m) a[m] = FD[SWX(idx0 + (m << lgs))];
        dft4(a);
        twiddle3(a, j, 1.0f / (float)(s << 2));
        #pragma unroll
        for (int p = 0; p < 4; ++p) FD[SWX(idx0 + (p << lgs))] = a[p];
        RBAR();
    }

    // ---- pass s=1 (trivial twiddle) ----
    {
        const int idx0 = tid << 2;
        float4 a[4];
        #pragma unroll
        for (int m = 0; m < 4; ++m) a[m] = FD[SWX(idx0 + m)];
        dft4(a);
        #pragma unroll
        for (int p = 0; p < 4; ++p) FD[SWX(idx0 + p)] = a[p];
    }
    RBAR();

    // ---- extract: group-major, fully coalesced (8 KB contiguous/WG) ----
    {
        uint2* base = Etg + ((size_t)b * 1024 + g) * 1024;
        #pragma unroll
        for (int it = 0; it < 4; ++it) {
            int s = tid + (it << 8);
            float4 v = FD[SWX(s)];
            uint2 u;
            u.x = pkh2(v.x, v.y);
            u.y = pkh2(v.z, v.w);
            base[s] = u;
        }
    }

    // ---- tf: clip + pack bin pairs, group-major, coalesced ----
    {
        const float* r0 = tf + ((size_t)b * NCELLS + c0) * NF;
        const float* r1 = r0 + NF;
        const float* r2 = r1 + NF;
        const float* r3 = r2 + NF;
        uint4* dst = TFtg + ((size_t)b * 1024 + g) * 257;
        for (int kp = tid; kp < NKP; kp += 256) {
            bool hv = kp < 256;
            uint4 u;
            u.x = pkh2(clip01(r0[2 * kp]), hv ? clip01(r0[2 * kp + 1]) : 0.0f);
            u.y = pkh2(clip01(r1[2 * kp]), hv ? clip01(r1[2 * kp + 1]) : 0.0f);
            u.z = pkh2(clip01(r2[2 * kp]), hv ? clip01(r2[2 * kp + 1]) : 0.0f);
            u.w = pkh2(clip01(r3[2 * kp]), hv ? clip01(r3[2 * kp + 1]) : 0.0f);
            dst[kp] = u;
        }
    }
}

// ---------------- T: layout transpose, all full-line ----------------
// bid < 4096: Et_g[b][g][s] -> Et2[b][s][g]   (64x64 uint2 tiles)
// bid >= 4096: TFt_g[b][g][kp] -> TFt4[b][kp][g] (32x32 uint4 tiles)
__global__ __launch_bounds__(256) void k_t(
    const uint2* __restrict__ Etg, uint2* __restrict__ Et2,
    const uint4* __restrict__ TFtg, uint4* __restrict__ TFt4)
{
    __shared__ unsigned LU[64 * 65 * 2];   // 33.3 KB, aliased by both roles
    const int tid = threadIdx.x;
    const int bid = blockIdx.x;

    if (bid < 4096) {
        unsigned* LA = LU;
        unsigned* LB = LU + 64 * 65;
        const int b = bid >> 8, tile = bid & 255;
        const int s0 = (tile >> 4) << 6, g0 = (tile & 15) << 6;
        #pragma unroll
        for (int j = 0; j < 16; ++j) {
            int idx = (j << 8) + tid;
            int gin = idx >> 6, sin = idx & 63;
            uint2 v = Etg[((size_t)b * 1024 + g0 + gin) * 1024 + s0 + sin];
            LA[gin * 65 + sin] = v.x;
            LB[gin * 65 + sin] = v.y;
        }
        __syncthreads();
        #pragma unroll
        for (int j = 0; j < 16; ++j) {
            int idx = (j << 8) + tid;
            int sin = idx >> 6, gin = idx & 63;
            uint2 v;
            v.x = LA[gin * 65 + sin];
            v.y = LB[gin * 65 + sin];
            Et2[((size_t)b * 1024 + s0 + sin) * 1024 + g0 + gin] = v;
        }
    } else {
        unsigned* P0 = LU;
        unsigned* P1 = LU + 1056;
        unsigned* P2 = LU + 2112;
        unsigned* P3 = LU + 3168;
        const int bid2 = bid - 4096;
        const int b = bid2 / 288, t2 = bid2 - b * 288;
        const int k0 = (t2 / 32) << 5, g0 = (t2 & 31) << 5;
        #pragma unroll
        for (int j = 0; j < 4; ++j) {
            int lin = (j << 8) + tid;
            int gin = lin >> 5, kin = lin & 31;
            int kp = k0 + kin;
            if (kp < NKP) {
                uint4 v = TFtg[((size_t)b * 1024 + g0 + gin) * 257 + kp];
                P0[gin * 33 + kin] = v.x;
                P1[gin * 33 + kin] = v.y;
                P2[gin * 33 + kin] = v.z;
                P3[gin * 33 + kin] = v.w;
            }
        }
        __syncthreads();
        #pragma unroll
        for (int j = 0; j < 4; ++j) {
            int lin = (j << 8) + tid;
            int kin = lin >> 5, gin = lin & 31;
            int kp = k0 + kin;
            if (kp < NKP) {
                uint4 v;
                v.x = P0[gin * 33 + kin];
                v.y = P1[gin * 33 + kin];
                v.z = P2[gin * 33 + kin];
                v.w = P3[gin * 33 + kin];
                TFt4[((size_t)b * 257 + kp) * 1024 + g0 + gin] = v;
            }
        }
    }
}

// ---------------- P2 ----------------
// Grid 512 x 1024 threads (round-14 verified). Thread q: x=q>>6, y=(q>>2)&15,
// z-slab (q&3)*4; pairs 2q,2q+1. z via shfl; y/x via 32KB swizzled LDS.
// WG0 = bins {0,512} (both exactly real), rows slotof4(0)=0 / slotof4(512)=2.
__global__ __launch_bounds__(1024, 8) void k_p2(
    const unsigned* __restrict__ Et, const unsigned* __restrict__ TFt,
    float2* __restrict__ ms)
{
    __shared__ float2 Sz[4096];        // 32 KB

    const int q    = threadIdx.x;
    const int lane = q & 63;
    const int k    = blockIdx.x;
    const bool dual = (k == 0);
    const int kp  = dual ? 0 : (k >> 1);
    const int sel = dual ? 0 : (k & 1);
    const int rA  = slotof4(dual ? 0 : k);
    const int rB  = slotof4(dual ? 512 : ((1024 - k) & 1023));
    const int x = q >> 6, y = (q >> 2) & 15, zs = (q & 3) << 2;

    #define AX(qq, dz) (((qq) << 2) | ((dz) ^ ((qq) & 3) ^ (((qq) >> 2) & 3)))

    float2 SF[4];
    #pragma unroll
    for (int dz = 0; dz < 4; ++dz) SF[dz] = make_float2(0.f, 0.f);

    #pragma unroll 1
    for (int b = 0; b < 16; ++b) {
        const uint2 ea = *(const uint2*)(Et + ((size_t)b * NFFT + rA) * NPAIR + 2 * q);
        const uint2 eb = *(const uint2*)(Et + ((size_t)b * NFFT + rB) * NPAIR + 2 * q);
        const uint4 tp = *(const uint4*)(TFt + ((size_t)b * NKP + kp) * NCELLS + 4 * q);
        uint4 tp2;
        if (dual) tp2 = *(const uint4*)(TFt + ((size_t)b * NKP + 256) * NCELLS + 4 * q);

        float2 T[4];
        if (!dual) {
            #pragma unroll
            for (int j = 0; j < 2; ++j) {
                unsigned fu = j ? ea.y : ea.x;
                unsigned gu = j ? eb.y : eb.x;
                float fr = h2lo(fu), fi = h2hi(fu);
                float gr = h2lo(gu), gi = h2hi(gu);
                float ear = 0.5f * (fr + gr), eai = 0.5f * (fi - gi);
                float ebr = 0.5f * (fi + gi), ebi = 0.5f * (gr - fr);
                unsigned te = cmp4(tp, 2 * j);
                unsigned to = cmp4(tp, 2 * j + 1);
                float re_ = sel ? h2hi(te) : h2lo(te);
                float ro_ = sel ? h2hi(to) : h2lo(to);
                T[2 * j]     = make_float2(re_ * (SF[2 * j].x + ear),
                                           re_ * (SF[2 * j].y + eai));
                T[2 * j + 1] = make_float2(ro_ * (SF[2 * j + 1].x + ebr),
                                           ro_ * (SF[2 * j + 1].y + ebi));
            }
        } else {
            #pragma unroll
            for (int dz = 0; dz < 4; ++dz) {
                unsigned fu = (dz >> 1) ? ea.y : ea.x;
                unsigned gu = (dz >> 1) ? eb.y : eb.x;
                float e0   = (dz & 1) ? h2hi(fu) : h2lo(fu);
                float e512 = (dz & 1) ? h2hi(gu) : h2lo(gu);
                float tA = h2lo(cmp4(tp, dz));
                float tB = h2lo(cmp4(tp2, dz));
                T[dz] = make_float2(tA * (SF[dz].x + e0),
                                    tB * (SF[dz].y + e512));
            }
        }
        if (q == 546) {                 // cell (8,8,8)
            if (dual) {
                ms[b * NF + 0]   = make_float2(T[0].x, 0.0f);
                ms[b * NF + 512] = make_float2(T[0].y, 0.0f);
            } else {
                ms[b * NF + k] = T[0];
            }
        }

        // z-sum: slab-internal + shfl partners q-1 / q+1
        float2 D, U;
        D.x = __shfl(T[3].x, lane - 1, 64); D.y = __shfl(T[3].y, lane - 1, 64);
        U.x = __shfl(T[0].x, lane + 1, 64); U.y = __shfl(T[0].y, lane + 1, 64);
        float2 Z[4];
        Z[0] = make_float2(T[0].x + T[1].x + (zs > 0 ? D.x : 0.f),
                           T[0].y + T[1].y + (zs > 0 ? D.y : 0.f));
        Z[1] = make_float2(T[0].x + T[1].x + T[2].x, T[0].y + T[1].y + T[2].y);
        Z[2] = make_float2(T[1].x + T[2].x + T[3].x, T[1].y + T[2].y + T[3].y);
        Z[3] = make_float2(T[2].x + T[3].x + (zs < 12 ? U.x : 0.f),
                           T[2].y + T[3].y + (zs < 12 ? U.y : 0.f));

        // y-sum via LDS (neighbor q +- 4)
        #pragma unroll
        for (int dz = 0; dz < 4; ++dz) Sz[AX(q, dz)] = Z[dz];
        __syncthreads();
        #pragma unroll
        for (int dz = 0; dz < 4; ++dz) {
            float2 s = Z[dz];
            if (y > 0)  { float2 u = Sz[AX(q - 4, dz)]; s.x += u.x; s.y += u.y; }
            if (y < 15) { float2 u = Sz[AX(q + 4, dz)]; s.x += u.x; s.y += u.y; }
            Z[dz] = s;
        }
        __syncthreads();
        // x-sum via LDS (neighbor q +- 64)
        #pragma unroll
        for (int dz = 0; dz < 4; ++dz) Sz[AX(q, dz)] = Z[dz];
        __syncthreads();
        #pragma unroll
        for (int dz = 0; dz < 4; ++dz) {
            float2 s = Z[dz];
            if (x > 0)  { float2 u = Sz[AX(q - 64, dz)]; s.x += u.x; s.y += u.y; }
            if (x < 15) { float2 u = Sz[AX(q + 64, dz)]; s.x += u.x; s.y += u.y; }
            SF[dz] = s;
        }
        __syncthreads();
    }
    #undef AX
}

// ---------------- P3 ----------------
__device__ __forceinline__ int pd(int i) { return i + (i >> 5); }

__global__ __launch_bounds__(256) void k_p3(
    const float2* __restrict__ ms, float* __restrict__ out)
{
    __shared__ float2 FD[1056];
    const int b = blockIdx.x, tid = threadIdx.x;

    for (int j = tid; j < NFFT; j += 256) {
        int jj = (j <= 512) ? j : 1024 - j;
        float2 v = ms[b * NF + jj];
        if (j > 512) v.y = -v.y;
        FD[pd(__brev(j) >> 22)] = v;
    }
    __syncthreads();

    for (int lg = 0; lg <= 9; ++lg) {
        const int len = 1 << lg;
        for (int pr = tid; pr < 512; pr += 256) {
            const int jj = pr & (len - 1);
            const int i0 = ((pr >> lg) << (lg + 1)) + jj;
            const int i1 = i0 + len;
            const int iw = jj << (9 - lg);
            float sn, cs;
            __sincosf(-PI2 * (1.0f / 1024.0f) * (float)iw, &sn, &cs);
            float2 a = FD[pd(i0)], bb = FD[pd(i1)];
            float tr = bb.x * cs + bb.y * sn;
            float ti = bb.y * cs - bb.x * sn;
            FD[pd(i0)] = make_float2(a.x + tr, a.y + ti);
            FD[pd(i1)] = make_float2(a.x - tr, a.y - ti);
        }
        __syncthreads();
    }
    for (int t = tid; t < NFFT; t += 256)
        out[b * NFFT + t] = FD[pd(t)].x * (1.0f / 1024.0f);
}

extern "C" void kernel_launch(void* const* d_in, const int* in_sizes, int n_in,
                              void* d_out, int out_size, void* d_ws, size_t ws_size,
                              hipStream_t stream)
{
    const float* tf    = (const float*)d_in[1];
    const float* imp   = (const float*)d_in[2];
    const float* noise = (const float*)d_in[3];
    float* out = (float*)d_out;

    uint2* Etg  = (uint2*)d_ws;                          // 16*1024*1024 uint2 (134 MB)
    uint2* Et2  = Etg + (size_t)16 * 1024 * 1024;        // 134 MB
    uint4* TFtg = (uint4*)(Et2 + (size_t)16 * 1024 * 1024);  // 16*1024*257 uint4 (67 MB)
    uint4* TFt4 = TFtg + (size_t)16 * 1024 * 257;        // 67 MB
    float2* ms  = (float2*)(TFt4 + (size_t)16 * 1024 * 257); // 16*513 c64

    k_p1<<<16384, 256, 0, stream>>>(tf, imp, noise, Etg, TFtg);
    k_t<<<8704, 256, 0, stream>>>(Etg, Et2, TFtg, TFt4);
    k_p2<<<512, 1024, 0, stream>>>((const unsigned*)Et2, (const unsigned*)TFt4, ms);
    k_p3<<<16, 256, 0, stream>>>(ms, out);
}

// Round 17
// 221.959 us; speedup vs baseline: 4.1518x; 1.0599x over previous
//
#include <hip/hip_runtime.h>

// Frequency-domain room sim, 5-kernel phase split.
//   SF = DFT(sound_field) per cell (unnormalized); per block b:
//     T = clip(res,0,1) * (SF + DFT(env_b));  mic_b = IDFT(T[mic])/1024;
//     SF = box3x3x3(T)   (pointwise per bin -> recursion independent per bin)
// k_tf: tf fp32 -> bin-major fp16 TFt4[b][kp][cell] DIRECTLY (LDS 64x64 tile
//       transpose, coalesced both sides). Removes tf from k_p1 and k_t.
// k_p1: radix-4^5 env FFTs, 4 pts/thread, 4 cells/WG, 16 KB LDS, 8 WG/CU.
//       Group-major contiguous Et stores (round-16 verified: the scattered
//       8-16B stores were the 253us wall). Final s=1 pass FUSED into the
//       extract (one less LDS round-trip + barrier; 4 RBARs total).
// k_t:  Et_g[b][g][slot] -> Et2[b][slot][pair] (64x64 uint2 LDS tiles).
// k_p2: 512 WGs x 1024 threads (round-14 verified form, byte-identical).
// k_p3: 16 inverse FFTs of the mic spectra.

#define NFFT   1024
#define NF     513
#define NKP    257
#define NCELLS 4096
#define NPAIR  2048
#define PI2    6.28318530717958647692f

// raw workgroup barrier: order LDS only; global loads/stores keep flowing
#define RBAR() do { \
    asm volatile("s_waitcnt lgkmcnt(0)" ::: "memory"); \
    __builtin_amdgcn_s_barrier(); \
    __builtin_amdgcn_sched_barrier(0); \
} while (0)

// float4-index XOR swizzle (round-15/16 verified)
__device__ __forceinline__ int SWX(int i) {
    return i ^ ((i >> 3) & 7) ^ ((i >> 6) & 7);
}
// base-4 digit reversal of a 10-bit index (5 digits)
__device__ __forceinline__ int slotof4(int k) {
    return ((k & 3) << 8) | (((k >> 2) & 3) << 6) | (((k >> 4) & 3) << 4) |
           (((k >> 6) & 3) << 2) | ((k >> 8) & 3);
}
__device__ __forceinline__ float clip01(float v) { return fminf(fmaxf(v, 0.0f), 1.0f); }
__device__ __forceinline__ unsigned pkh2(float a, float b) {
    union { _Float16 h[2]; unsigned u; } z;
    z.h[0] = (_Float16)a; z.h[1] = (_Float16)b;
    return z.u;
}
__device__ __forceinline__ float h2lo(unsigned u) {
    union { unsigned u; _Float16 h[2]; } z; z.u = u; return (float)z.h[0];
}
__device__ __forceinline__ float h2hi(unsigned u) {
    union { unsigned u; _Float16 h[2]; } z; z.u = u; return (float)z.h[1];
}
__device__ __forceinline__ unsigned cmp4(const uint4& v, int c) {
    return c == 0 ? v.x : c == 1 ? v.y : c == 2 ? v.z : v.w;
}
__device__ __forceinline__ float4 f4add(float4 a, float4 b) {
    return make_float4(a.x + b.x, a.y + b.y, a.z + b.z, a.w + b.w);
}
__device__ __forceinline__ float4 f4sub(float4 a, float4 b) {
    return make_float4(a.x - b.x, a.y - b.y, a.z - b.z, a.w - b.w);
}
__device__ __forceinline__ float4 cmul2(float4 d, float2 w) {
    return make_float4(d.x * w.x - d.y * w.y, d.x * w.y + d.y * w.x,
                       d.z * w.x - d.w * w.y, d.z * w.y + d.w * w.x);
}
__device__ __forceinline__ float4 nI(float4 v) { return make_float4(v.y, -v.x, v.w, -v.z); }
__device__ __forceinline__ float4 pI(float4 v) { return make_float4(-v.y, v.x, -v.w, v.z); }

__device__ __forceinline__ void dft4(float4* a) {
    float4 e = f4add(a[0], a[2]), f = f4add(a[1], a[3]);
    float4 g = f4sub(a[0], a[2]), h = f4sub(a[1], a[3]);
    a[0] = f4add(e, f);
    a[2] = f4sub(e, f);
    a[1] = f4add(g, nI(h));
    a[3] = f4add(g, pI(h));
}

__device__ __forceinline__ void twiddle3(float4* a, int j, float invL) {
    float sv, cv;
    __sincosf(-PI2 * (float)j * invL, &sv, &cv);
    float2 w1 = make_float2(cv, sv), wp = w1;
    a[1] = cmul2(a[1], wp);
    wp = make_float2(wp.x * w1.x - wp.y * w1.y, wp.x * w1.y + wp.y * w1.x);
    a[2] = cmul2(a[2], wp);
    wp = make_float2(wp.x * w1.x - wp.y * w1.y, wp.x * w1.y + wp.y * w1.x);
    a[3] = cmul2(a[3], wp);
}

// ---------------- k_tf: tf -> bin-major fp16, direct ----------------
// Grid 16 * 64 * 9. Tile = 64 cells x 32 kp (f range 64). kt==8: kp=256 only.
__global__ __launch_bounds__(256) void k_tf(
    const float* __restrict__ tf, uint4* __restrict__ TFt4)
{
    __shared__ float L[64 * 66];
    const int tid = threadIdx.x;
    const int bid = blockIdx.x;
    const int b = bid / 576;
    const int rem = bid - b * 576;
    const int ct = rem / 9, kt = rem - ct * 9;
    const int c0 = ct << 6;

    if (kt < 8) {
        const int k0 = kt << 5;          // kp base; f base = 2*k0
        #pragma unroll
        for (int j = 0; j < 16; ++j) {
            int idx = (j << 8) + tid;
            int cin = idx >> 6, fin = idx & 63;
            L[cin * 66 + fin] =
                clip01(tf[((size_t)b * NCELLS + c0 + cin) * NF + 2 * k0 + fin]);
        }
        __syncthreads();
        #pragma unroll
        for (int j = 0; j < 2; ++j) {
            int idx = (j << 8) + tid;
            int kpl = idx >> 4, gl = idx & 15;   // 32 kp x 16 g
            int cb = gl << 2;
            uint4 u;
            u.x = pkh2(L[(cb + 0) * 66 + 2 * kpl], L[(cb + 0) * 66 + 2 * kpl + 1]);
            u.y = pkh2(L[(cb + 1) * 66 + 2 * kpl], L[(cb + 1) * 66 + 2 * kpl + 1]);
            u.z = pkh2(L[(cb + 2) * 66 + 2 * kpl], L[(cb + 2) * 66 + 2 * kpl + 1]);
            u.w = pkh2(L[(cb + 3) * 66 + 2 * kpl], L[(cb + 3) * 66 + 2 * kpl + 1]);
            TFt4[((size_t)b * NKP + k0 + kpl) * 1024 + (c0 >> 2) + gl] = u;
        }
    } else {
        // kp = 256: only f = 512 (imag half zero)
        if (tid < 64)
            L[tid] = clip01(tf[((size_t)b * NCELLS + c0 + tid) * NF + 512]);
        __syncthreads();
        if (tid < 16) {
            int cb = tid << 2;
            uint4 u;
            u.x = pkh2(L[cb + 0], 0.0f);
            u.y = pkh2(L[cb + 1], 0.0f);
            u.z = pkh2(L[cb + 2], 0.0f);
            u.w = pkh2(L[cb + 3], 0.0f);
            TFt4[((size_t)b * NKP + 256) * 1024 + (c0 >> 2) + tid] = u;
        }
    }
}

// ---------------- P1 ----------------
// Grid 16384 = 16 blocks x 1024 groups. WG = group g = cells 4g..4g+3.
__global__ __launch_bounds__(256, 8) void k_p1(
    const float* __restrict__ imp, const float* __restrict__ noise,
    uint2* __restrict__ Etg)
{
    __shared__ float4 FD[1024];        // exactly 16 KB

    const int tid = threadIdx.x;
    const int bid = blockIdx.x;
    const int b   = bid >> 10;
    const int g   = bid & 1023;
    const int c0  = g << 2;

    // ---- env + pass0 (s=256) from registers ----
    {
        const float* nz = noise + ((size_t)b * NCELLS + c0) * (size_t)NFFT + tid;
        float nzv[16];
        #pragma unroll
        for (int m = 0; m < 4; ++m)
            #pragma unroll
            for (int cc = 0; cc < 4; ++cc)
                nzv[4 * m + cc] = nz[cc * NFFT + (m << 8)];

        const float* ipr = imp + ((size_t)b * NCELLS + c0) * 16;
        float4 a[4];
        #pragma unroll
        for (int m = 0; m < 4; ++m) {
            int n = tid + (m << 8);
            float coord = (n + 0.5f) * (16.0f / 1024.0f) - 0.5f;
            coord = fminf(fmaxf(coord, 0.0f), 15.0f);
            int lo = (int)coord;
            int hi = lo + 1 > 15 ? 15 : lo + 1;
            float wl = coord - (float)lo, wh = 1.0f - wl;
            float4 e;
            e.x = clip01(ipr[lo]      * wh + ipr[hi]      * wl) * nzv[4 * m + 0];
            e.y = clip01(ipr[16 + lo] * wh + ipr[16 + hi] * wl) * nzv[4 * m + 1];
            e.z = clip01(ipr[32 + lo] * wh + ipr[32 + hi] * wl) * nzv[4 * m + 2];
            e.w = clip01(ipr[48 + lo] * wh + ipr[48 + hi] * wl) * nzv[4 * m + 3];
            a[m] = e;
        }
        dft4(a);
        twiddle3(a, tid, 1.0f / 1024.0f);
        #pragma unroll
        for (int p = 0; p < 4; ++p) FD[SWX(tid + (p << 8))] = a[p];
    }
    RBAR();

    // ---- passes s = 64, 16, 4 ----
    #pragma unroll
    for (int pi = 0; pi < 3; ++pi) {
        const int lgs = 6 - 2 * pi;
        const int s   = 1 << lgs;
        const int j   = tid & (s - 1);
        const int idx0 = ((tid >> lgs) << (lgs + 2)) | j;
        float4 a[4];
        #pragma unroll
        for (int m = 0; m < 4; ++m) a[m] = FD[SWX(idx0 + (m << lgs))];
        dft4(a);
        twiddle3(a, j, 1.0f / (float)(s << 2));
        #pragma unroll
        for (int p = 0; p < 4; ++p) FD[SWX(idx0 + (p << lgs))] = a[p];
        RBAR();
    }

    // ---- pass s=1 (trivial twiddle) FUSED into extract ----
    // thread owns slots 4*tid..4*tid+3 -> dft4 in regs -> 32B contiguous store
    {
        const int t4 = tid << 2;
        float4 a[4];
        #pragma unroll
        for (int m = 0; m < 4; ++m) a[m] = FD[SWX(t4 + m)];
        dft4(a);
        uint2* base = Etg + ((size_t)b * 1024 + g) * 1024 + t4;
        uint4 u0 = { pkh2(a[0].x, a[0].y), pkh2(a[0].z, a[0].w),
                     pkh2(a[1].x, a[1].y), pkh2(a[1].z, a[1].w) };
        uint4 u1 = { pkh2(a[2].x, a[2].y), pkh2(a[2].z, a[2].w),
                     pkh2(a[3].x, a[3].y), pkh2(a[3].z, a[3].w) };
        *(uint4*)(base)     = u0;
        *(uint4*)(base + 2) = u1;
    }
}

// ---------------- k_t: Et layout transpose, all full-line ----------------
// Et_g[b][g][s] -> Et2[b][s][g]   (64x64 uint2 tiles). Grid 4096.
__global__ __launch_bounds__(256) void k_t(
    const uint2* __restrict__ Etg, uint2* __restrict__ Et2)
{
    __shared__ unsigned LA[64 * 65], LB[64 * 65];
    const int tid = threadIdx.x;
    const int bid = blockIdx.x;
    const int b = bid >> 8, tile = bid & 255;
    const int s0 = (tile >> 4) << 6, g0 = (tile & 15) << 6;

    #pragma unroll
    for (int j = 0; j < 16; ++j) {
        int idx = (j << 8) + tid;
        int gin = idx >> 6, sin = idx & 63;
        uint2 v = Etg[((size_t)b * 1024 + g0 + gin) * 1024 + s0 + sin];
        LA[gin * 65 + sin] = v.x;
        LB[gin * 65 + sin] = v.y;
    }
    __syncthreads();
    #pragma unroll
    for (int j = 0; j < 16; ++j) {
        int idx = (j << 8) + tid;
        int sin = idx >> 6, gin = idx & 63;
        uint2 v;
        v.x = LA[gin * 65 + sin];
        v.y = LB[gin * 65 + sin];
        Et2[((size_t)b * 1024 + s0 + sin) * 1024 + g0 + gin] = v;
    }
}

// ---------------- P2 ----------------
// Grid 512 x 1024 threads (round-14 verified). Thread q: x=q>>6, y=(q>>2)&15,
// z-slab (q&3)*4; pairs 2q,2q+1. z via shfl; y/x via 32KB swizzled LDS.
// WG0 = bins {0,512} (both exactly real), rows slotof4(0)=0 / slotof4(512)=2.
__global__ __launch_bounds__(1024, 8) void k_p2(
    const unsigned* __restrict__ Et, const unsigned* __restrict__ TFt,
    float2* __restrict__ ms)
{
    __shared__ float2 Sz[4096];        // 32 KB

    const int q    = threadIdx.x;
    const int lane = q & 63;
    const int k    = blockIdx.x;
    const bool dual = (k == 0);
    const int kp  = dual ? 0 : (k >> 1);
    const int sel = dual ? 0 : (k & 1);
    const int rA  = slotof4(dual ? 0 : k);
    const int rB  = slotof4(dual ? 512 : ((1024 - k) & 1023));
    const int x = q >> 6, y = (q >> 2) & 15, zs = (q & 3) << 2;

    #define AX(qq, dz) (((qq) << 2) | ((dz) ^ ((qq) & 3) ^ (((qq) >> 2) & 3)))

    float2 SF[4];
    #pragma unroll
    for (int dz = 0; dz < 4; ++dz) SF[dz] = make_float2(0.f, 0.f);

    #pragma unroll 1
    for (int b = 0; b < 16; ++b) {
        const uint2 ea = *(const uint2*)(Et + ((size_t)b * NFFT + rA) * NPAIR + 2 * q);
        const uint2 eb = *(const uint2*)(Et + ((size_t)b * NFFT + rB) * NPAIR + 2 * q);
        const uint4 tp = *(const uint4*)(TFt + ((size_t)b * NKP + kp) * NCELLS + 4 * q);
        uint4 tp2;
        if (dual) tp2 = *(const uint4*)(TFt + ((size_t)b * NKP + 256) * NCELLS + 4 * q);

        float2 T[4];
        if (!dual) {
            #pragma unroll
            for (int j = 0; j < 2; ++j) {
                unsigned fu = j ? ea.y : ea.x;
                unsigned gu = j ? eb.y : eb.x;
                float fr = h2lo(fu), fi = h2hi(fu);
                float gr = h2lo(gu), gi = h2hi(gu);
                float ear = 0.5f * (fr + gr), eai = 0.5f * (fi - gi);
                float ebr = 0.5f * (fi + gi), ebi = 0.5f * (gr - fr);
                unsigned te = cmp4(tp, 2 * j);
                unsigned to = cmp4(tp, 2 * j + 1);
                float re_ = sel ? h2hi(te) : h2lo(te);
                float ro_ = sel ? h2hi(to) : h2lo(to);
                T[2 * j]     = make_float2(re_ * (SF[2 * j].x + ear),
                                           re_ * (SF[2 * j].y + eai));
                T[2 * j + 1] = make_float2(ro_ * (SF[2 * j + 1].x + ebr),
                                           ro_ * (SF[2 * j + 1].y + ebi));
            }
        } else {
            #pragma unroll
            for (int dz = 0; dz < 4; ++dz) {
                unsigned fu = (dz >> 1) ? ea.y : ea.x;
                unsigned gu = (dz >> 1) ? eb.y : eb.x;
                float e0   = (dz & 1) ? h2hi(fu) : h2lo(fu);
                float e512 = (dz & 1) ? h2hi(gu) : h2lo(gu);
                float tA = h2lo(cmp4(tp, dz));
                float tB = h2lo(cmp4(tp2, dz));
                T[dz] = make_float2(tA * (SF[dz].x + e0),
                                    tB * (SF[dz].y + e512));
            }
        }
        if (q == 546) {                 // cell (8,8,8)
            if (dual) {
                ms[b * NF + 0]   = make_float2(T[0].x, 0.0f);
                ms[b * NF + 512] = make_float2(T[0].y, 0.0f);
            } else {
                ms[b * NF + k] = T[0];
            }
        }

        // z-sum: slab-internal + shfl partners q-1 / q+1
        float2 D, U;
        D.x = __shfl(T[3].x, lane - 1, 64); D.y = __shfl(T[3].y, lane - 1, 64);
        U.x = __shfl(T[0].x, lane + 1, 64); U.y = __shfl(T[0].y, lane + 1, 64);
        float2 Z[4];
        Z[0] = make_float2(T[0].x + T[1].x + (zs > 0 ? D.x : 0.f),
                           T[0].y + T[1].y + (zs > 0 ? D.y : 0.f));
        Z[1] = make_float2(T[0].x + T[1].x + T[2].x, T[0].y + T[1].y + T[2].y);
        Z[2] = make_float2(T[1].x + T[2].x + T[3].x, T[1].y + T[2].y + T[3].y);
        Z[3] = make_float2(T[2].x + T[3].x + (zs < 12 ? U.x : 0.f),
                           T[2].y + T[3].y + (zs < 12 ? U.y : 0.f));

        // y-sum via LDS (neighbor q +- 4)
        #pragma unroll
        for (int dz = 0; dz < 4; ++dz) Sz[AX(q, dz)] = Z[dz];
        __syncthreads();
        #pragma unroll
        for (int dz = 0; dz < 4; ++dz) {
            float2 s = Z[dz];
            if (y > 0)  { float2 u = Sz[AX(q - 4, dz)]; s.x += u.x; s.y += u.y; }
            if (y < 15) { float2 u = Sz[AX(q + 4, dz)]; s.x += u.x; s.y += u.y; }
            Z[dz] = s;
        }
        __syncthreads();
        // x-sum via LDS (neighbor q +- 64)
        #pragma unroll
        for (int dz = 0; dz < 4; ++dz) Sz[AX(q, dz)] = Z[dz];
        __syncthreads();
        #pragma unroll
        for (int dz = 0; dz < 4; ++dz) {
            float2 s = Z[dz];
            if (x > 0)  { float2 u = Sz[AX(q - 64, dz)]; s.x += u.x; s.y += u.y; }
            if (x < 15) { float2 u = Sz[AX(q + 64, dz)]; s.x += u.x; s.y += u.y; }
            SF[dz] = s;
        }
        __syncthreads();
    }
    #undef AX
}

// ---------------- P3 ----------------
__device__ __forceinline__ int pd(int i) { return i + (i >> 5); }

__global__ __launch_bounds__(256) void k_p3(
    const float2* __restrict__ ms, float* __restrict__ out)
{
    __shared__ float2 FD[1056];
    const int b = blockIdx.x, tid = threadIdx.x;

    for (int j = tid; j < NFFT; j += 256) {
        int jj = (j <= 512) ? j : 1024 - j;
        float2 v = ms[b * NF + jj];
        if (j > 512) v.y = -v.y;
        FD[pd(__brev(j) >> 22)] = v;
    }
    __syncthreads();

    for (int lg = 0; lg <= 9; ++lg) {
        const int len = 1 << lg;
        for (int pr = tid; pr < 512; pr += 256) {
            const int jj = pr & (len - 1);
            const int i0 = ((pr >> lg) << (lg + 1)) + jj;
            const int i1 = i0 + len;
            const int iw = jj << (9 - lg);
            float sn, cs;
            __sincosf(-PI2 * (1.0f / 1024.0f) * (float)iw, &sn, &cs);
            float2 a = FD[pd(i0)], bb = FD[pd(i1)];
            float tr = bb.x * cs + bb.y * sn;
            float ti = bb.y * cs - bb.x * sn;
            FD[pd(i0)] = make_float2(a.x + tr, a.y + ti);
            FD[pd(i1)] = make_float2(a.x - tr, a.y - ti);
        }
        __syncthreads();
    }
    for (int t = tid; t < NFFT; t += 256)
        out[b * NFFT + t] = FD[pd(t)].x * (1.0f / 1024.0f);
}

extern "C" void kernel_launch(void* const* d_in, const int* in_sizes, int n_in,
                              void* d_out, int out_size, void* d_ws, size_t ws_size,
                              hipStream_t stream)
{
    const float* tf    = (const float*)d_in[1];
    const float* imp   = (const float*)d_in[2];
    const float* noise = (const float*)d_in[3];
    float* out = (float*)d_out;

    uint2* Etg  = (uint2*)d_ws;                              // 134 MB
    uint2* Et2  = Etg + (size_t)16 * 1024 * 1024;            // 134 MB
    uint4* TFt4 = (uint4*)(Et2 + (size_t)16 * 1024 * 1024);  // 67 MB
    float2* ms  = (float2*)(TFt4 + (size_t)16 * NKP * 1024);

    k_tf<<<16 * 64 * 9, 256, 0, stream>>>(tf, TFt4);
    k_p1<<<16384, 256, 0, stream>>>(imp, noise, Etg);
    k_t<<<4096, 256, 0, stream>>>(Etg, Et2);
    k_p2<<<512, 1024, 0, stream>>>((const unsigned*)Et2, (const unsigned*)TFt4, ms);
    k_p3<<<16, 256, 0, stream>>>(ms, out);
}

// Round 18
// 217.888 us; speedup vs baseline: 4.2293x; 1.0187x over previous
//
#include <hip/hip_runtime.h>

// Frequency-domain room sim, 4-kernel phase split.
//   SF = DFT(sound_field) per cell (unnormalized); per block b:
//     T = clip(res,0,1) * (SF + DFT(env_b));  mic_b = IDFT(T[mic])/1024;
//     SF = box3x3x3(T)   (pointwise per bin -> recursion independent per bin)
// k_p1tf: MERGED k_p1 + k_tf (independent work, overlapped by grid partition;
//     round-17 ran them serially at 120+33us with p1 only 37% VALU / 32% HBM).
//     bid<16384: radix-4^5 env FFT, 4 cells/WG, group-major Et stores
//     (round-16: scattered 8-16B stores were the 253us wall), s=1 pass fused
//     into extract. bid>=16384: tf fp32 -> bin-major fp16 TFt4 tile transpose.
// k_t:  Et_g[b][g][slot] -> Et2[b][slot][pair] (64x64 uint2 LDS tiles).
// k_p2: 512 WGs x 1024 threads (round-14 verified form, byte-identical).
// k_p3: 16 inverse FFTs of the mic spectra.

#define NFFT   1024
#define NF     513
#define NKP    257
#define NCELLS 4096
#define NPAIR  2048
#define PI2    6.28318530717958647692f

// raw workgroup barrier: order LDS only; global loads/stores keep flowing
#define RBAR() do { \
    asm volatile("s_waitcnt lgkmcnt(0)" ::: "memory"); \
    __builtin_amdgcn_s_barrier(); \
    __builtin_amdgcn_sched_barrier(0); \
} while (0)

// float4-index XOR swizzle (round-15/16 verified)
__device__ __forceinline__ int SWX(int i) {
    return i ^ ((i >> 3) & 7) ^ ((i >> 6) & 7);
}
// base-4 digit reversal of a 10-bit index (5 digits)
__device__ __forceinline__ int slotof4(int k) {
    return ((k & 3) << 8) | (((k >> 2) & 3) << 6) | (((k >> 4) & 3) << 4) |
           (((k >> 6) & 3) << 2) | ((k >> 8) & 3);
}
__device__ __forceinline__ float clip01(float v) { return fminf(fmaxf(v, 0.0f), 1.0f); }
__device__ __forceinline__ unsigned pkh2(float a, float b) {
    union { _Float16 h[2]; unsigned u; } z;
    z.h[0] = (_Float16)a; z.h[1] = (_Float16)b;
    return z.u;
}
__device__ __forceinline__ float h2lo(unsigned u) {
    union { unsigned u; _Float16 h[2]; } z; z.u = u; return (float)z.h[0];
}
__device__ __forceinline__ float h2hi(unsigned u) {
    union { unsigned u; _Float16 h[2]; } z; z.u = u; return (float)z.h[1];
}
__device__ __forceinline__ unsigned cmp4(const uint4& v, int c) {
    return c == 0 ? v.x : c == 1 ? v.y : c == 2 ? v.z : v.w;
}
__device__ __forceinline__ float4 f4add(float4 a, float4 b) {
    return make_float4(a.x + b.x, a.y + b.y, a.z + b.z, a.w + b.w);
}
__device__ __forceinline__ float4 f4sub(float4 a, float4 b) {
    return make_float4(a.x - b.x, a.y - b.y, a.z - b.z, a.w - b.w);
}
__device__ __forceinline__ float4 cmul2(float4 d, float2 w) {
    return make_float4(d.x * w.x - d.y * w.y, d.x * w.y + d.y * w.x,
                       d.z * w.x - d.w * w.y, d.z * w.y + d.w * w.x);
}
__device__ __forceinline__ float4 nI(float4 v) { return make_float4(v.y, -v.x, v.w, -v.z); }
__device__ __forceinline__ float4 pI(float4 v) { return make_float4(-v.y, v.x, -v.w, v.z); }

__device__ __forceinline__ void dft4(float4* a) {
    float4 e = f4add(a[0], a[2]), f = f4add(a[1], a[3]);
    float4 g = f4sub(a[0], a[2]), h = f4sub(a[1], a[3]);
    a[0] = f4add(e, f);
    a[2] = f4sub(e, f);
    a[1] = f4add(g, nI(h));
    a[3] = f4add(g, pI(h));
}

__device__ __forceinline__ void twiddle3(float4* a, int j, float invL) {
    float sv, cv;
    __sincosf(-PI2 * (float)j * invL, &sv, &cv);
    float2 w1 = make_float2(cv, sv), wp = w1;
    a[1] = cmul2(a[1], wp);
    wp = make_float2(wp.x * w1.x - wp.y * w1.y, wp.x * w1.y + wp.y * w1.x);
    a[2] = cmul2(a[2], wp);
    wp = make_float2(wp.x * w1.x - wp.y * w1.y, wp.x * w1.y + wp.y * w1.x);
    a[3] = cmul2(a[3], wp);
}

// ---------------- k_p1tf: merged env-FFT + tf-transpose ----------------
// Grid 16384 + 9216. Shared 17.6 KB pool -> still 8 WG/CU.
__global__ __launch_bounds__(256, 8) void k_p1tf(
    const float* __restrict__ tf, const float* __restrict__ imp,
    const float* __restrict__ noise, uint2* __restrict__ Etg,
    uint4* __restrict__ TFt4)
{
    __shared__ float4 POOL[1100];      // 17600 B (p1: 1024 float4; tf: 4224 f)

    const int tid = threadIdx.x;
    const int bid = blockIdx.x;

    if (bid < 16384) {
        // ================= P1 role =================
        float4* FD = POOL;
        const int b   = bid >> 10;
        const int g   = bid & 1023;
        const int c0  = g << 2;

        // ---- env + pass0 (s=256) from registers ----
        {
            const float* nz = noise + ((size_t)b * NCELLS + c0) * (size_t)NFFT + tid;
            float nzv[16];
            #pragma unroll
            for (int m = 0; m < 4; ++m)
                #pragma unroll
                for (int cc = 0; cc < 4; ++cc)
                    nzv[4 * m + cc] = nz[cc * NFFT + (m << 8)];

            const float* ipr = imp + ((size_t)b * NCELLS + c0) * 16;
            float4 a[4];
            #pragma unroll
            for (int m = 0; m < 4; ++m) {
                int n = tid + (m << 8);
                float coord = (n + 0.5f) * (16.0f / 1024.0f) - 0.5f;
                coord = fminf(fmaxf(coord, 0.0f), 15.0f);
                int lo = (int)coord;
                int hi = lo + 1 > 15 ? 15 : lo + 1;
                float wl = coord - (float)lo, wh = 1.0f - wl;
                float4 e;
                e.x = clip01(ipr[lo]      * wh + ipr[hi]      * wl) * nzv[4 * m + 0];
                e.y = clip01(ipr[16 + lo] * wh + ipr[16 + hi] * wl) * nzv[4 * m + 1];
                e.z = clip01(ipr[32 + lo] * wh + ipr[32 + hi] * wl) * nzv[4 * m + 2];
                e.w = clip01(ipr[48 + lo] * wh + ipr[48 + hi] * wl) * nzv[4 * m + 3];
                a[m] = e;
            }
            dft4(a);
            twiddle3(a, tid, 1.0f / 1024.0f);
            #pragma unroll
            for (int p = 0; p < 4; ++p) FD[SWX(tid + (p << 8))] = a[p];
        }
        RBAR();

        // ---- passes s = 64, 16, 4 ----
        #pragma unroll
        for (int pi = 0; pi < 3; ++pi) {
            const int lgs = 6 - 2 * pi;
            const int s   = 1 << lgs;
            const int j   = tid & (s - 1);
            const int idx0 = ((tid >> lgs) << (lgs + 2)) | j;
            float4 a[4];
            #pragma unroll
            for (int m = 0; m < 4; ++m) a[m] = FD[SWX(idx0 + (m << lgs))];
            dft4(a);
            twiddle3(a, j, 1.0f / (float)(s << 2));
            #pragma unroll
            for (int p = 0; p < 4; ++p) FD[SWX(idx0 + (p << lgs))] = a[p];
            RBAR();
        }

        // ---- pass s=1 FUSED into extract: 32B contiguous store ----
        {
            const int t4 = tid << 2;
            float4 a[4];
            #pragma unroll
            for (int m = 0; m < 4; ++m) a[m] = FD[SWX(t4 + m)];
            dft4(a);
            uint2* base = Etg + ((size_t)b * 1024 + g) * 1024 + t4;
            uint4 u0 = { pkh2(a[0].x, a[0].y), pkh2(a[0].z, a[0].w),
                         pkh2(a[1].x, a[1].y), pkh2(a[1].z, a[1].w) };
            uint4 u1 = { pkh2(a[2].x, a[2].y), pkh2(a[2].z, a[2].w),
                         pkh2(a[3].x, a[3].y), pkh2(a[3].z, a[3].w) };
            *(uint4*)(base)     = u0;
            *(uint4*)(base + 2) = u1;
        }
    } else {
        // ================= TF role =================
        float* L = (float*)POOL;       // 64 x 66 floats = 16896 B
        const int bid2 = bid - 16384;
        const int b = bid2 / 576;
        const int rem = bid2 - b * 576;
        const int ct = rem / 9, kt = rem - ct * 9;
        const int c0 = ct << 6;

        if (kt < 8) {
            const int k0 = kt << 5;      // kp base; f base = 2*k0
            #pragma unroll
            for (int j = 0; j < 16; ++j) {
                int idx = (j << 8) + tid;
                int cin = idx >> 6, fin = idx & 63;
                L[cin * 66 + fin] =
                    clip01(tf[((size_t)b * NCELLS + c0 + cin) * NF + 2 * k0 + fin]);
            }
            __syncthreads();
            #pragma unroll
            for (int j = 0; j < 2; ++j) {
                int idx = (j << 8) + tid;
                int kpl = idx >> 4, gl = idx & 15;   // 32 kp x 16 g
                int cb = gl << 2;
                uint4 u;
                u.x = pkh2(L[(cb + 0) * 66 + 2 * kpl], L[(cb + 0) * 66 + 2 * kpl + 1]);
                u.y = pkh2(L[(cb + 1) * 66 + 2 * kpl], L[(cb + 1) * 66 + 2 * kpl + 1]);
                u.z = pkh2(L[(cb + 2) * 66 + 2 * kpl], L[(cb + 2) * 66 + 2 * kpl + 1]);
                u.w = pkh2(L[(cb + 3) * 66 + 2 * kpl], L[(cb + 3) * 66 + 2 * kpl + 1]);
                TFt4[((size_t)b * NKP + k0 + kpl) * 1024 + (c0 >> 2) + gl] = u;
            }
        } else {
            // kp = 256: only f = 512 (imag half zero)
            if (tid < 64)
                L[tid] = clip01(tf[((size_t)b * NCELLS + c0 + tid) * NF + 512]);
            __syncthreads();
            if (tid < 16) {
                int cb = tid << 2;
                uint4 u;
                u.x = pkh2(L[cb + 0], 0.0f);
                u.y = pkh2(L[cb + 1], 0.0f);
                u.z = pkh2(L[cb + 2], 0.0f);
                u.w = pkh2(L[cb + 3], 0.0f);
                TFt4[((size_t)b * NKP + 256) * 1024 + (c0 >> 2) + tid] = u;
            }
        }
    }
}

// ---------------- k_t: Et layout transpose, all full-line ----------------
// Et_g[b][g][s] -> Et2[b][s][g]   (64x64 uint2 tiles). Grid 4096.
__global__ __launch_bounds__(256) void k_t(
    const uint2* __restrict__ Etg, uint2* __restrict__ Et2)
{
    __shared__ unsigned LA[64 * 65], LB[64 * 65];
    const int tid = threadIdx.x;
    const int bid = blockIdx.x;
    const int b = bid >> 8, tile = bid & 255;
    const int s0 = (tile >> 4) << 6, g0 = (tile & 15) << 6;

    #pragma unroll
    for (int j = 0; j < 16; ++j) {
        int idx = (j << 8) + tid;
        int gin = idx >> 6, sin = idx & 63;
        uint2 v = Etg[((size_t)b * 1024 + g0 + gin) * 1024 + s0 + sin];
        LA[gin * 65 + sin] = v.x;
        LB[gin * 65 + sin] = v.y;
    }
    __syncthreads();
    #pragma unroll
    for (int j = 0; j < 16; ++j) {
        int idx = (j << 8) + tid;
        int sin = idx >> 6, gin = idx & 63;
        uint2 v;
        v.x = LA[gin * 65 + sin];
        v.y = LB[gin * 65 + sin];
        Et2[((size_t)b * 1024 + s0 + sin) * 1024 + g0 + gin] = v;
    }
}

// ---------------- P2 ----------------
// Grid 512 x 1024 threads (round-14 verified). Thread q: x=q>>6, y=(q>>2)&15,
// z-slab (q&3)*4; pairs 2q,2q+1. z via shfl; y/x via 32KB swizzled LDS.
// WG0 = bins {0,512} (both exactly real), rows slotof4(0)=0 / slotof4(512)=2.
__global__ __launch_bounds__(1024, 8) void k_p2(
    const unsigned* __restrict__ Et, const unsigned* __restrict__ TFt,
    float2* __restrict__ ms)
{
    __shared__ float2 Sz[4096];        // 32 KB

    const int q    = threadIdx.x;
    const int lane = q & 63;
    const int k    = blockIdx.x;
    const bool dual = (k == 0);
    const int kp  = dual ? 0 : (k >> 1);
    const int sel = dual ? 0 : (k & 1);
    const int rA  = slotof4(dual ? 0 : k);
    const int rB  = slotof4(dual ? 512 : ((1024 - k) & 1023));
    const int x = q >> 6, y = (q >> 2) & 15, zs = (q & 3) << 2;

    #define AX(qq, dz) (((qq) << 2) | ((dz) ^ ((qq) & 3) ^ (((qq) >> 2) & 3)))

    float2 SF[4];
    #pragma unroll
    for (int dz = 0; dz < 4; ++dz) SF[dz] = make_float2(0.f, 0.f);

    #pragma unroll 1
    for (int b = 0; b < 16; ++b) {
        const uint2 ea = *(const uint2*)(Et + ((size_t)b * NFFT + rA) * NPAIR + 2 * q);
        const uint2 eb = *(const uint2*)(Et + ((size_t)b * NFFT + rB) * NPAIR + 2 * q);
        const uint4 tp = *(const uint4*)(TFt + ((size_t)b * NKP + kp) * NCELLS + 4 * q);
        uint4 tp2;
        if (dual) tp2 = *(const uint4*)(TFt + ((size_t)b * NKP + 256) * NCELLS + 4 * q);

        float2 T[4];
        if (!dual) {
            #pragma unroll
            for (int j = 0; j < 2; ++j) {
                unsigned fu = j ? ea.y : ea.x;
                unsigned gu = j ? eb.y : eb.x;
                float fr = h2lo(fu), fi = h2hi(fu);
                float gr = h2lo(gu), gi = h2hi(gu);
                float ear = 0.5f * (fr + gr), eai = 0.5f * (fi - gi);
                float ebr = 0.5f * (fi + gi), ebi = 0.5f * (gr - fr);
                unsigned te = cmp4(tp, 2 * j);
                unsigned to = cmp4(tp, 2 * j + 1);
                float re_ = sel ? h2hi(te) : h2lo(te);
                float ro_ = sel ? h2hi(to) : h2lo(to);
                T[2 * j]     = make_float2(re_ * (SF[2 * j].x + ear),
                                           re_ * (SF[2 * j].y + eai));
                T[2 * j + 1] = make_float2(ro_ * (SF[2 * j + 1].x + ebr),
                                           ro_ * (SF[2 * j + 1].y + ebi));
            }
        } else {
            #pragma unroll
            for (int dz = 0; dz < 4; ++dz) {
                unsigned fu = (dz >> 1) ? ea.y : ea.x;
                unsigned gu = (dz >> 1) ? eb.y : eb.x;
                float e0   = (dz & 1) ? h2hi(fu) : h2lo(fu);
                float e512 = (dz & 1) ? h2hi(gu) : h2lo(gu);
                float tA = h2lo(cmp4(tp, dz));
                float tB = h2lo(cmp4(tp2, dz));
                T[dz] = make_float2(tA * (SF[dz].x + e0),
                                    tB * (SF[dz].y + e512));
            }
        }
        if (q == 546) {                 // cell (8,8,8)
            if (dual) {
                ms[b * NF + 0]   = make_float2(T[0].x, 0.0f);
                ms[b * NF + 512] = make_float2(T[0].y, 0.0f);
            } else {
                ms[b * NF + k] = T[0];
            }
        }

        // z-sum: slab-internal + shfl partners q-1 / q+1
        float2 D, U;
        D.x = __shfl(T[3].x, lane - 1, 64); D.y = __shfl(T[3].y, lane - 1, 64);
        U.x = __shfl(T[0].x, lane + 1, 64); U.y = __shfl(T[0].y, lane + 1, 64);
        float2 Z[4];
        Z[0] = make_float2(T[0].x + T[1].x + (zs > 0 ? D.x : 0.f),
                           T[0].y + T[1].y + (zs > 0 ? D.y : 0.f));
        Z[1] = make_float2(T[0].x + T[1].x + T[2].x, T[0].y + T[1].y + T[2].y);
        Z[2] = make_float2(T[1].x + T[2].x + T[3].x, T[1].y + T[2].y + T[3].y);
        Z[3] = make_float2(T[2].x + T[3].x + (zs < 12 ? U.x : 0.f),
                           T[2].y + T[3].y + (zs < 12 ? U.y : 0.f));

        // y-sum via LDS (neighbor q +- 4)
        #pragma unroll
        for (int dz = 0; dz < 4; ++dz) Sz[AX(q, dz)] = Z[dz];
        __syncthreads();
        #pragma unroll
        for (int dz = 0; dz < 4; ++dz) {
            float2 s = Z[dz];
            if (y > 0)  { float2 u = Sz[AX(q - 4, dz)]; s.x += u.x; s.y += u.y; }
            if (y < 15) { float2 u = Sz[AX(q + 4, dz)]; s.x += u.x; s.y += u.y; }
            Z[dz] = s;
        }
        __syncthreads();
        // x-sum via LDS (neighbor q +- 64)
        #pragma unroll
        for (int dz = 0; dz < 4; ++dz) Sz[AX(q, dz)] = Z[dz];
        __syncthreads();
        #pragma unroll
        for (int dz = 0; dz < 4; ++dz) {
            float2 s = Z[dz];
            if (x > 0)  { float2 u = Sz[AX(q - 64, dz)]; s.x += u.x; s.y += u.y; }
            if (x < 15) { float2 u = Sz[AX(q + 64, dz)]; s.x += u.x; s.y += u.y; }
            SF[dz] = s;
        }
        __syncthreads();
    }
    #undef AX
}

// ---------------- P3 ----------------
__device__ __forceinline__ int pd(int i) { return i + (i >> 5); }

__global__ __launch_bounds__(256) void k_p3(
    const float2* __restrict__ ms, float* __restrict__ out)
{
    __shared__ float2 FD[1056];
    const int b = blockIdx.x, tid = threadIdx.x;

    for (int j = tid; j < NFFT; j += 256) {
        int jj = (j <= 512) ? j : 1024 - j;
        float2 v = ms[b * NF + jj];
        if (j > 512) v.y = -v.y;
        FD[pd(__brev(j) >> 22)] = v;
    }
    __syncthreads();

    for (int lg = 0; lg <= 9; ++lg) {
        const int len = 1 << lg;
        for (int pr = tid; pr < 512; pr += 256) {
            const int jj = pr & (len - 1);
            const int i0 = ((pr >> lg) << (lg + 1)) + jj;
            const int i1 = i0 + len;
            const int iw = jj << (9 - lg);
            float sn, cs;
            __sincosf(-PI2 * (1.0f / 1024.0f) * (float)iw, &sn, &cs);
            float2 a = FD[pd(i0)], bb = FD[pd(i1)];
            float tr = bb.x * cs + bb.y * sn;
            float ti = bb.y * cs - bb.x * sn;
            FD[pd(i0)] = make_float2(a.x + tr, a.y + ti);
            FD[pd(i1)] = make_float2(a.x - tr, a.y - ti);
        }
        __syncthreads();
    }
    for (int t = tid; t < NFFT; t += 256)
        out[b * NFFT + t] = FD[pd(t)].x * (1.0f / 1024.0f);
}

extern "C" void kernel_launch(void* const* d_in, const int* in_sizes, int n_in,
                              void* d_out, int out_size, void* d_ws, size_t ws_size,
                              hipStream_t stream)
{
    const float* tf    = (const float*)d_in[1];
    const float* imp   = (const float*)d_in[2];
    const float* noise = (const float*)d_in[3];
    float* out = (float*)d_out;

    uint2* Etg  = (uint2*)d_ws;                              // 134 MB
    uint2* Et2  = Etg + (size_t)16 * 1024 * 1024;            // 134 MB
    uint4* TFt4 = (uint4*)(Et2 + (size_t)16 * 1024 * 1024);  // 67 MB
    float2* ms  = (float2*)(TFt4 + (size_t)16 * NKP * 1024);

    k_p1tf<<<16384 + 9216, 256, 0, stream>>>(tf, imp, noise, Etg, TFt4);
    k_t<<<4096, 256, 0, stream>>>(Etg, Et2);
    k_p2<<<512, 1024, 0, stream>>>((const unsigned*)Et2, (const unsigned*)TFt4, ms);
    k_p3<<<16, 256, 0, stream>>>(ms, out);
}